// Round 1
// baseline (29001.187 us; speedup 1.0000x reference)
//
#include <hip/hip_runtime.h>
#include <cmath>

namespace {

constexpr int LAYERS = 12;
constexpr int H   = 768;
constexpr int NH  = 12;
constexpr int DH  = 64;
constexpr int FF  = 3072;
constexpr int V   = 21128;
constexpr int S   = 512;
constexpr int B   = 8;
constexpr int M   = B * S;          // 4096 tokens
constexpr int SEP = 102;
constexpr int NT  = (V + 63) / 64;  // 331 column tiles for logits

__device__ __forceinline__ float geluf(float x) {
  return 0.5f * x * (1.0f + erff(x * 0.70710678118654752f));
}

__device__ __forceinline__ float block_sum256(float v, float* red) {
  int tid = threadIdx.x;
  red[tid] = v; __syncthreads();
  for (int s2 = 128; s2 > 0; s2 >>= 1) {
    if (tid < s2) red[tid] += red[tid + s2];
    __syncthreads();
  }
  float r = red[0];
  __syncthreads();
  return r;
}

__device__ __forceinline__ float block_max256(float v, float* red) {
  int tid = threadIdx.x;
  red[tid] = v; __syncthreads();
  for (int s2 = 128; s2 > 0; s2 >>= 1) {
    if (tid < s2) red[tid] = fmaxf(red[tid], red[tid + s2]);
    __syncthreads();
  }
  float r = red[0];
  __syncthreads();
  return r;
}

// ---------------- sep position per batch row ----------------
__global__ void sep_kernel(const int* __restrict__ ids, int* __restrict__ sep) {
  int b = blockIdx.x;
  __shared__ int red[256];
  int m = S - 1;
  for (int s = threadIdx.x; s < S; s += 256)
    if (ids[b * S + s] == SEP) m = min(m, s);
  red[threadIdx.x] = m; __syncthreads();
  for (int s2 = 128; s2 > 0; s2 >>= 1) {
    if (threadIdx.x < s2) red[threadIdx.x] = min(red[threadIdx.x], red[threadIdx.x + s2]);
    __syncthreads();
  }
  if (threadIdx.x == 0) sep[b] = red[0];
}

// ---------------- embedding + LN ----------------
__global__ __launch_bounds__(256) void embed_kernel(
    const int* __restrict__ ids, const float* __restrict__ we,
    const float* __restrict__ pe, const float* __restrict__ te,
    const float* __restrict__ g, const float* __restrict__ bta,
    float* __restrict__ x) {
  __shared__ float red[256];
  int tok = blockIdx.x;
  int s = tok % S;
  int id = ids[tok];
  float vals[3];
  #pragma unroll
  for (int i = 0; i < 3; i++) {
    int hh = threadIdx.x + i * 256;
    vals[i] = we[(size_t)id * H + hh] + pe[(size_t)s * H + hh] + te[hh];
  }
  float mean = block_sum256(vals[0] + vals[1] + vals[2], red) * (1.0f / H);
  float sq = 0.f;
  #pragma unroll
  for (int i = 0; i < 3; i++) { float d = vals[i] - mean; sq += d * d; }
  float var = block_sum256(sq, red) * (1.0f / H);
  float inv = rsqrtf(var + 1e-12f);
  #pragma unroll
  for (int i = 0; i < 3; i++) {
    int hh = threadIdx.x + i * 256;
    x[(size_t)tok * H + hh] = (vals[i] - mean) * inv * g[hh] + bta[hh];
  }
}

// ---------------- residual + LN ----------------
__global__ __launch_bounds__(256) void add_ln_kernel(
    const float* __restrict__ resid, const float* __restrict__ t,
    const float* __restrict__ g, const float* __restrict__ bta,
    float* __restrict__ out) {
  __shared__ float red[256];
  int tok = blockIdx.x;
  float vals[3];
  #pragma unroll
  for (int i = 0; i < 3; i++) {
    int hh = threadIdx.x + i * 256;
    vals[i] = resid[(size_t)tok * H + hh] + t[(size_t)tok * H + hh];
  }
  float mean = block_sum256(vals[0] + vals[1] + vals[2], red) * (1.0f / H);
  float sq = 0.f;
  #pragma unroll
  for (int i = 0; i < 3; i++) { float d = vals[i] - mean; sq += d * d; }
  float var = block_sum256(sq, red) * (1.0f / H);
  float inv = rsqrtf(var + 1e-12f);
  #pragma unroll
  for (int i = 0; i < 3; i++) {
    int hh = threadIdx.x + i * 256;
    out[(size_t)tok * H + hh] = (vals[i] - mean) * inv * g[hh] + bta[hh];
  }
}

// ---------------- generic tiled f32 GEMM: C = act(A @ W + bias) ----------------
// A [M,K] row-major, W [K,N] row-major, C [M,N]. M%64==0, K%16==0, N guarded.
template <int ACT>
__global__ __launch_bounds__(256) void gemm_kernel(
    const float* __restrict__ A, const float* __restrict__ W,
    const float* __restrict__ bias, float* __restrict__ C,
    int N, int K) {
  __shared__ float As[64][17];
  __shared__ float Bs[16][64];
  int tid = threadIdx.x;
  int tx = tid & 15, ty = tid >> 4;
  int row0 = blockIdx.y * 64;
  int col0 = blockIdx.x * 64;
  float acc[4][4] = {};
  for (int k0 = 0; k0 < K; k0 += 16) {
    #pragma unroll
    for (int i = 0; i < 4; i++) {
      int idx = tid + i * 256;
      int r = idx >> 4, c = idx & 15;
      As[r][c] = A[(size_t)(row0 + r) * K + k0 + c];
    }
    #pragma unroll
    for (int i = 0; i < 4; i++) {
      int idx = tid + i * 256;
      int r = idx >> 6, c = idx & 63;
      int col = col0 + c;
      Bs[r][c] = (col < N) ? W[(size_t)(k0 + r) * N + col] : 0.f;
    }
    __syncthreads();
    #pragma unroll
    for (int kk = 0; kk < 16; kk++) {
      float a[4], bv[4];
      #pragma unroll
      for (int i = 0; i < 4; i++) a[i] = As[ty * 4 + i][kk];
      #pragma unroll
      for (int j = 0; j < 4; j++) bv[j] = Bs[kk][tx * 4 + j];
      #pragma unroll
      for (int i = 0; i < 4; i++)
        #pragma unroll
        for (int j = 0; j < 4; j++)
          acc[i][j] += a[i] * bv[j];
    }
    __syncthreads();
  }
  #pragma unroll
  for (int i = 0; i < 4; i++) {
    int row = row0 + ty * 4 + i;
    #pragma unroll
    for (int j = 0; j < 4; j++) {
      int col = col0 + tx * 4 + j;
      if (col < N) {
        float vv = acc[i][j] + bias[col];
        if (ACT == 1) vv = geluf(vv);
        C[(size_t)row * N + col] = vv;
      }
    }
  }
}

// ---------------- attention: one block per (b, head, q) ----------------
__global__ __launch_bounds__(256) void attn_kernel(
    const float* __restrict__ q, const float* __restrict__ k,
    const float* __restrict__ v, const int* __restrict__ sep,
    float* __restrict__ ctx) {
  int qi = blockIdx.x, h = blockIdx.y, b = blockIdx.z;
  __shared__ float qv[DH];
  __shared__ float sc[S];
  __shared__ float red[256];
  __shared__ float cpart[4][DH];
  int tid = threadIdx.x;
  if (tid < DH) qv[tid] = q[((size_t)(b * S + qi) * H) + h * DH + tid];
  __syncthreads();
  int sepb = sep[b];
  bool qpref = (qi <= sepb);
  for (int kk = tid; kk < S; kk += 256) {
    const float* krow = k + ((size_t)(b * S + kk) * H) + h * DH;
    float acc = 0.f;
    #pragma unroll
    for (int d = 0; d < DH; d++) acc += qv[d] * krow[d];
    bool allowed = (kk <= qi) || (qpref && kk <= sepb);
    sc[kk] = acc * 0.125f + (allowed ? 0.f : -1e4f);
  }
  __syncthreads();
  float lm = -INFINITY;
  for (int kk = tid; kk < S; kk += 256) lm = fmaxf(lm, sc[kk]);
  float Mx = block_max256(lm, red);
  float ls = 0.f;
  for (int kk = tid; kk < S; kk += 256) {
    float e = __expf(sc[kk] - Mx);
    sc[kk] = e;
    ls += e;
  }
  __syncthreads();
  float Ssum = block_sum256(ls, red);
  float inv = 1.0f / Ssum;
  int d = tid & 63, part = tid >> 6;
  float acc = 0.f;
  for (int kk = part * 128; kk < part * 128 + 128; kk++)
    acc += sc[kk] * v[((size_t)(b * S + kk) * H) + h * DH + d];
  cpart[part][d] = acc;
  __syncthreads();
  if (tid < DH) {
    float r = (cpart[0][tid] + cpart[1][tid] + cpart[2][tid] + cpart[3][tid]) * inv;
    ctx[((size_t)(b * S + qi) * H) + h * DH + tid] = r;
  }
}

// ---------------- logits GEMM with fused per-tile softmax partials ----------------
// Writes per-(row, 64-col-tile) (max, sumexp) to partials, and the label logit.
__global__ __launch_bounds__(256) void gemm_logits_kernel(
    const float* __restrict__ A, const float* __restrict__ W,
    const float* __restrict__ bias, const int* __restrict__ labels,
    float2* __restrict__ partials, float* __restrict__ lablogit,
    int N, int K) {
  __shared__ float As[64][17];
  __shared__ float Bs[16][64];
  __shared__ float rowbuf[64][17];
  __shared__ float rmax[64];
  int tid = threadIdx.x;
  int tx = tid & 15, ty = tid >> 4;
  int row0 = blockIdx.y * 64;
  int col0 = blockIdx.x * 64;
  float acc[4][4] = {};
  for (int k0 = 0; k0 < K; k0 += 16) {
    #pragma unroll
    for (int i = 0; i < 4; i++) {
      int idx = tid + i * 256;
      int r = idx >> 4, c = idx & 15;
      As[r][c] = A[(size_t)(row0 + r) * K + k0 + c];
    }
    #pragma unroll
    for (int i = 0; i < 4; i++) {
      int idx = tid + i * 256;
      int r = idx >> 6, c = idx & 63;
      int col = col0 + c;
      Bs[r][c] = (col < N) ? W[(size_t)(k0 + r) * N + col] : 0.f;
    }
    __syncthreads();
    #pragma unroll
    for (int kk = 0; kk < 16; kk++) {
      float a[4], bv[4];
      #pragma unroll
      for (int i = 0; i < 4; i++) a[i] = As[ty * 4 + i][kk];
      #pragma unroll
      for (int j = 0; j < 4; j++) bv[j] = Bs[kk][tx * 4 + j];
      #pragma unroll
      for (int i = 0; i < 4; i++)
        #pragma unroll
        for (int j = 0; j < 4; j++)
          acc[i][j] += a[i] * bv[j];
    }
    __syncthreads();
  }
  // epilogue: bias, label capture, per-row-tile max/sumexp
  float vals[4][4];
  #pragma unroll
  for (int i = 0; i < 4; i++) {
    int row = row0 + ty * 4 + i;
    int lab = labels[row];
    float rm = -INFINITY;
    #pragma unroll
    for (int j = 0; j < 4; j++) {
      int col = col0 + tx * 4 + j;
      if (col < N) {
        float vv = acc[i][j] + bias[col];
        vals[i][j] = vv;
        if (col == lab) lablogit[row] = vv;
        rm = fmaxf(rm, vv);
      } else {
        vals[i][j] = -INFINITY;
      }
    }
    rowbuf[ty * 4 + i][tx] = rm;
  }
  __syncthreads();
  if (tid < 64) {
    float m = -INFINITY;
    #pragma unroll
    for (int t = 0; t < 16; t++) m = fmaxf(m, rowbuf[tid][t]);
    rmax[tid] = m;
  }
  __syncthreads();
  #pragma unroll
  for (int i = 0; i < 4; i++) {
    float m = rmax[ty * 4 + i];
    float ssum = 0.f;
    #pragma unroll
    for (int j = 0; j < 4; j++) {
      int col = col0 + tx * 4 + j;
      if (col < N) ssum += __expf(vals[i][j] - m);
    }
    rowbuf[ty * 4 + i][tx] = ssum;
  }
  __syncthreads();
  if (tid < 64) {
    float ssum = 0.f;
    #pragma unroll
    for (int t = 0; t < 16; t++) ssum += rowbuf[tid][t];
    partials[(size_t)(row0 + tid) * NT + blockIdx.x] = make_float2(rmax[tid], ssum);
  }
}

// ---------------- per-token nll + accumulate ----------------
__global__ __launch_bounds__(256) void loss_kernel(
    const float2* __restrict__ partials, const float* __restrict__ lablogit,
    const int* __restrict__ labels, float* __restrict__ acc) {
  int tok = blockIdx.x;
  if (labels[tok] < 0) return;
  __shared__ float red[256];
  float lm = -INFINITY;
  for (int t = threadIdx.x; t < NT; t += 256)
    lm = fmaxf(lm, partials[(size_t)tok * NT + t].x);
  float Mx = block_max256(lm, red);
  float ls = 0.f;
  for (int t = threadIdx.x; t < NT; t += 256) {
    float2 p = partials[(size_t)tok * NT + t];
    ls += p.y * __expf(p.x - Mx);
  }
  float Ssum = block_sum256(ls, red);
  if (threadIdx.x == 0) {
    float nll = (Mx + logf(Ssum)) - lablogit[tok];
    atomicAdd(&acc[0], nll);
    atomicAdd(&acc[1], 1.0f);
  }
}

__global__ void finalize_kernel(const float* __restrict__ acc, float* __restrict__ out) {
  out[0] = acc[0] / fmaxf(acc[1], 1.0f);
}

}  // namespace

extern "C" void kernel_launch(void* const* d_in, const int* in_sizes, int n_in,
                              void* d_out, int out_size, void* d_ws, size_t ws_size,
                              hipStream_t stream) {
  const int*   input_ids = (const int*)d_in[0];
  const int*   labels    = (const int*)d_in[1];
  const float* word_emb  = (const float*)d_in[2];
  const float* pos_emb   = (const float*)d_in[3];
  const float* type_emb  = (const float*)d_in[4];
  const float* emb_ln_g  = (const float*)d_in[5];
  const float* emb_ln_b  = (const float*)d_in[6];
  const float* Wq = (const float*)d_in[7];
  const float* bq = (const float*)d_in[8];
  const float* Wk = (const float*)d_in[9];
  const float* bk = (const float*)d_in[10];
  const float* Wv = (const float*)d_in[11];
  const float* bv = (const float*)d_in[12];
  const float* Wo = (const float*)d_in[13];
  const float* bo = (const float*)d_in[14];
  const float* ln1_g = (const float*)d_in[15];
  const float* ln1_b = (const float*)d_in[16];
  const float* Wi = (const float*)d_in[17];
  const float* bi = (const float*)d_in[18];
  const float* Wd = (const float*)d_in[19];
  const float* bd = (const float*)d_in[20];
  const float* ln2_g = (const float*)d_in[21];
  const float* ln2_b = (const float*)d_in[22];
  const float* Wc = (const float*)d_in[23];
  const float* bc = (const float*)d_in[24];

  float* ws = (float*)d_ws;
  const size_t MH = (size_t)M * H;        // 3,145,728
  size_t off = 0;
  float* x    = ws + off; off += MH;
  float* qb   = ws + off; off += MH;
  float* kb   = ws + off; off += MH;
  float* vb   = ws + off; off += MH;
  float* ctx  = ws + off; off += MH;
  float* t2   = ws + off; off += MH;
  float* t1   = ws + off; off += (size_t)M * FF;
  float2* partials = (float2*)(ws + off); off += (size_t)M * NT * 2;
  float* lablogit = ws + off; off += M;
  float* acc = ws + off; off += 2;
  int* sep = (int*)(ws + off); off += B;

  hipMemsetAsync(acc, 0, 2 * sizeof(float), stream);

  sep_kernel<<<B, 256, 0, stream>>>(input_ids, sep);
  embed_kernel<<<M, 256, 0, stream>>>(input_ids, word_emb, pos_emb, type_emb,
                                      emb_ln_g, emb_ln_b, x);

  dim3 gH((H + 63) / 64, M / 64);
  dim3 gF((FF + 63) / 64, M / 64);
  dim3 gAttn(S, NH, B);

  for (int l = 0; l < LAYERS; l++) {
    const float* wq = Wq + (size_t)l * H * H;
    const float* wk = Wk + (size_t)l * H * H;
    const float* wv = Wv + (size_t)l * H * H;
    const float* wo = Wo + (size_t)l * H * H;
    const float* wi = Wi + (size_t)l * H * FF;
    const float* wd = Wd + (size_t)l * FF * H;

    gemm_kernel<0><<<gH, 256, 0, stream>>>(x, wq, bq + (size_t)l * H, qb, H, H);
    gemm_kernel<0><<<gH, 256, 0, stream>>>(x, wk, bk + (size_t)l * H, kb, H, H);
    gemm_kernel<0><<<gH, 256, 0, stream>>>(x, wv, bv + (size_t)l * H, vb, H, H);
    attn_kernel<<<gAttn, 256, 0, stream>>>(qb, kb, vb, sep, ctx);
    gemm_kernel<0><<<gH, 256, 0, stream>>>(ctx, wo, bo + (size_t)l * H, t2, H, H);
    add_ln_kernel<<<M, 256, 0, stream>>>(x, t2, ln1_g + (size_t)l * H,
                                         ln1_b + (size_t)l * H, x);
    gemm_kernel<1><<<gF, 256, 0, stream>>>(x, wi, bi + (size_t)l * FF, t1, FF, H);
    gemm_kernel<0><<<gH, 256, 0, stream>>>(t1, wd, bd + (size_t)l * H, t2, H, FF);
    add_ln_kernel<<<M, 256, 0, stream>>>(x, t2, ln2_g + (size_t)l * H,
                                         ln2_b + (size_t)l * H, x);
  }

  dim3 gV(NT, M / 64);
  gemm_logits_kernel<<<gV, 256, 0, stream>>>(x, Wc, bc, labels, partials, lablogit, V, H);
  loss_kernel<<<M, 256, 0, stream>>>(partials, lablogit, labels, acc);
  finalize_kernel<<<1, 1, 0, stream>>>(acc, (float*)d_out);
}

// Round 2
// 9091.294 us; speedup vs baseline: 3.1900x; 3.1900x over previous
//
#include <hip/hip_runtime.h>
#include <hip/hip_bf16.h>
#include <cmath>

namespace {

constexpr int LAYERS = 12;
constexpr int H   = 768;
constexpr int NH  = 12;
constexpr int DH  = 64;
constexpr int FF  = 3072;
constexpr int V   = 21128;
constexpr int S   = 512;
constexpr int B   = 8;
constexpr int M   = B * S;            // 4096 tokens
constexpr int SEP = 102;
constexpr int NPAD = 21248;           // V padded to multiple of 128
constexpr int NT64 = NPAD / 64;       // 332 column half-tiles for logits

typedef __attribute__((ext_vector_type(8))) short short8;
typedef __attribute__((ext_vector_type(4))) float floatx4;

__device__ __forceinline__ float geluf(float x) {
  return 0.5f * x * (1.0f + erff(x * 0.70710678118654752f));
}

__device__ __forceinline__ void gload16(const void* g, void* l) {
  __builtin_amdgcn_global_load_lds(
      (const __attribute__((address_space(1))) void*)g,
      (__attribute__((address_space(3))) void*)l, 16, 0, 0);
}

__device__ __forceinline__ float bflo(unsigned int u) { return __uint_as_float(u << 16); }
__device__ __forceinline__ float bfhi(unsigned int u) { return __uint_as_float(u & 0xffff0000u); }

__device__ __forceinline__ float block_sum256(float v, float* red) {
  int tid = threadIdx.x;
  red[tid] = v; __syncthreads();
  for (int s2 = 128; s2 > 0; s2 >>= 1) {
    if (tid < s2) red[tid] += red[tid + s2];
    __syncthreads();
  }
  float r = red[0];
  __syncthreads();
  return r;
}

__device__ __forceinline__ float block_max256(float v, float* red) {
  int tid = threadIdx.x;
  red[tid] = v; __syncthreads();
  for (int s2 = 128; s2 > 0; s2 >>= 1) {
    if (tid < s2) red[tid] = fmaxf(red[tid], red[tid + s2]);
    __syncthreads();
  }
  float r = red[0];
  __syncthreads();
  return r;
}

// ---------------- sep position per batch row ----------------
__global__ void sep_kernel(const int* __restrict__ ids, int* __restrict__ sep) {
  int b = blockIdx.x;
  __shared__ int red[256];
  int m = S - 1;
  for (int s = threadIdx.x; s < S; s += 256)
    if (ids[b * S + s] == SEP) m = min(m, s);
  red[threadIdx.x] = m; __syncthreads();
  for (int s2 = 128; s2 > 0; s2 >>= 1) {
    if (threadIdx.x < s2) red[threadIdx.x] = min(red[threadIdx.x], red[threadIdx.x + s2]);
    __syncthreads();
  }
  if (threadIdx.x == 0) sep[b] = red[0];
}

// ---------------- weight transpose + f32->bf16: W[K,N] -> Wt[Npad,K] ----------------
__global__ __launch_bounds__(256) void transpose_kernel(
    const float* __restrict__ W, __hip_bfloat16* __restrict__ Wt,
    int K, int N, int Npad, size_t in_stride, size_t out_stride) {
  const float* Wz = W + (size_t)blockIdx.z * in_stride;
  __hip_bfloat16* Wtz = Wt + (size_t)blockIdx.z * out_stride;
  __shared__ float tile[32][33];
  int k0 = blockIdx.x * 32, n0 = blockIdx.y * 32;
  int tx = threadIdx.x & 31, ty = threadIdx.x >> 5;  // 32 x 8
  #pragma unroll
  for (int i = 0; i < 4; i++) {
    int kk = k0 + ty + i * 8, nn = n0 + tx;
    tile[ty + i * 8][tx] = (kk < K && nn < N) ? Wz[(size_t)kk * N + nn] : 0.f;
  }
  __syncthreads();
  #pragma unroll
  for (int i = 0; i < 4; i++) {
    int nn = n0 + ty + i * 8, kk = k0 + tx;
    if (nn < Npad && kk < K)
      Wtz[(size_t)nn * K + kk] = __float2bfloat16(tile[tx][ty + i * 8]);
  }
}

// ---------------- embedding + LN (writes f32 x and bf16 xb) ----------------
__global__ __launch_bounds__(256) void embed_kernel(
    const int* __restrict__ ids, const float* __restrict__ we,
    const float* __restrict__ pe, const float* __restrict__ te,
    const float* __restrict__ g, const float* __restrict__ bta,
    float* __restrict__ x, __hip_bfloat16* __restrict__ xb) {
  __shared__ float red[256];
  int tok = blockIdx.x;
  int s = tok % S;
  int id = ids[tok];
  float vals[3];
  #pragma unroll
  for (int i = 0; i < 3; i++) {
    int hh = threadIdx.x + i * 256;
    vals[i] = we[(size_t)id * H + hh] + pe[(size_t)s * H + hh] + te[hh];
  }
  float mean = block_sum256(vals[0] + vals[1] + vals[2], red) * (1.0f / H);
  float sq = 0.f;
  #pragma unroll
  for (int i = 0; i < 3; i++) { float d = vals[i] - mean; sq += d * d; }
  float var = block_sum256(sq, red) * (1.0f / H);
  float inv = rsqrtf(var + 1e-12f);
  #pragma unroll
  for (int i = 0; i < 3; i++) {
    int hh = threadIdx.x + i * 256;
    float o = (vals[i] - mean) * inv * g[hh] + bta[hh];
    x[(size_t)tok * H + hh] = o;
    xb[(size_t)tok * H + hh] = __float2bfloat16(o);
  }
}

// ---------------- residual + LN (writes f32 x and bf16 xb) ----------------
__global__ __launch_bounds__(256) void add_ln_kernel(
    const float* __restrict__ resid, const float* __restrict__ t,
    const float* __restrict__ g, const float* __restrict__ bta,
    float* __restrict__ out, __hip_bfloat16* __restrict__ outb) {
  __shared__ float red[256];
  int tok = blockIdx.x;
  float vals[3];
  #pragma unroll
  for (int i = 0; i < 3; i++) {
    int hh = threadIdx.x + i * 256;
    vals[i] = resid[(size_t)tok * H + hh] + t[(size_t)tok * H + hh];
  }
  float mean = block_sum256(vals[0] + vals[1] + vals[2], red) * (1.0f / H);
  float sq = 0.f;
  #pragma unroll
  for (int i = 0; i < 3; i++) { float d = vals[i] - mean; sq += d * d; }
  float var = block_sum256(sq, red) * (1.0f / H);
  float inv = rsqrtf(var + 1e-12f);
  #pragma unroll
  for (int i = 0; i < 3; i++) {
    int hh = threadIdx.x + i * 256;
    float o = (vals[i] - mean) * inv * g[hh] + bta[hh];
    out[(size_t)tok * H + hh] = o;
    outb[(size_t)tok * H + hh] = __float2bfloat16(o);
  }
}

// ---------------- MFMA bf16 GEMM: C = epi(A @ Bt^T + bias) ----------------
// A bf16 [M,K] row-major; Bt bf16 [N,K] row-major (pre-transposed weights).
// 128x128 tile, BK=32, 4 waves as 2x2 of 64x64, v_mfma_f32_16x16x32_bf16.
// EPI: 0 = f32 store; 1 = bf16 store; 2 = gelu + bf16 store; 3 = logits partials.
template <int K, int N, int EPI>
__global__ __launch_bounds__(256) void mfma_gemm(
    const short* __restrict__ A, const short* __restrict__ Bt,
    const float* __restrict__ bias,
    float* __restrict__ Cf, __hip_bfloat16* __restrict__ Cb,
    const int* __restrict__ labels, float2* __restrict__ partials,
    float* __restrict__ lablogit) {
  __shared__ __align__(16) short lds_a[128 * 32];
  __shared__ __align__(16) short lds_b[128 * 32];
  const int tid = threadIdx.x, lane = tid & 63, w = tid >> 6;
  const int wm = w >> 1, wn = w & 1;
  const int row0 = blockIdx.y * 128, col0 = blockIdx.x * 128;
  const int g = lane >> 4, c16 = lane & 15;
  const int srow = w * 32 + (lane >> 2);  // staging row (w's 32-row slice)
  const int schunk = lane & 3;            // 16B chunk within 64B row
  floatx4 acc[4][4] = {};

  for (int k0 = 0; k0 < K; k0 += 32) {
    #pragma unroll
    for (int j = 0; j < 2; j++) {
      int m = srow + j * 16;
      int cg = schunk ^ ((m >> 1) & 3);   // XOR swizzle: breaks 8-way ds_read conflicts
      gload16(A + (size_t)(row0 + m) * K + (k0 + cg * 8), lds_a + w * 1024 + j * 512);
      gload16(Bt + (size_t)(col0 + m) * K + (k0 + cg * 8), lds_b + w * 1024 + j * 512);
    }
    __syncthreads();
    short8 af[4], bfr[4];
    #pragma unroll
    for (int t = 0; t < 4; t++) {
      int rm = wm * 64 + t * 16 + c16;
      af[t] = *(const short8*)(lds_a + rm * 32 + ((g ^ ((rm >> 1) & 3)) << 3));
      int rn = wn * 64 + t * 16 + c16;
      bfr[t] = *(const short8*)(lds_b + rn * 32 + ((g ^ ((rn >> 1) & 3)) << 3));
    }
    #pragma unroll
    for (int mt = 0; mt < 4; mt++)
      #pragma unroll
      for (int nt = 0; nt < 4; nt++)
        acc[mt][nt] = __builtin_amdgcn_mfma_f32_16x16x32_bf16(af[mt], bfr[nt], acc[mt][nt], 0, 0, 0);
    __syncthreads();
  }

  // epilogue: C/D layout col = lane&15, row = (lane>>4)*4 + r
  if constexpr (EPI == 0) {
    #pragma unroll
    for (int mt = 0; mt < 4; mt++)
      #pragma unroll
      for (int r = 0; r < 4; r++) {
        int row = row0 + wm * 64 + mt * 16 + g * 4 + r;
        #pragma unroll
        for (int nt = 0; nt < 4; nt++) {
          int col = col0 + wn * 64 + nt * 16 + c16;
          Cf[(size_t)row * N + col] = acc[mt][nt][r] + bias[col];
        }
      }
  } else if constexpr (EPI == 1 || EPI == 2) {
    #pragma unroll
    for (int mt = 0; mt < 4; mt++)
      #pragma unroll
      for (int r = 0; r < 4; r++) {
        int row = row0 + wm * 64 + mt * 16 + g * 4 + r;
        #pragma unroll
        for (int nt = 0; nt < 4; nt++) {
          int col = col0 + wn * 64 + nt * 16 + c16;
          float vv = acc[mt][nt][r] + bias[col];
          if constexpr (EPI == 2) vv = geluf(vv);
          Cb[(size_t)row * N + col] = __float2bfloat16(vv);
        }
      }
  } else {
    // logits: per-(row, 64-col half-tile) (max, sumexp) + label logit capture
    #pragma unroll
    for (int mt = 0; mt < 4; mt++)
      #pragma unroll
      for (int r = 0; r < 4; r++) {
        int row = row0 + wm * 64 + mt * 16 + g * 4 + r;
        int lab = labels[row];
        float vals[4];
        float rmax = -1e30f;
        #pragma unroll
        for (int nt = 0; nt < 4; nt++) {
          int col = col0 + wn * 64 + nt * 16 + c16;
          float vv = (col < V) ? (acc[mt][nt][r] + bias[col]) : -60000.0f;
          vals[nt] = vv;
          rmax = fmaxf(rmax, vv);
          if (col == lab) lablogit[row] = vv;
        }
        #pragma unroll
        for (int d = 1; d < 16; d <<= 1) rmax = fmaxf(rmax, __shfl_xor(rmax, d, 64));
        float se = 0.f;
        #pragma unroll
        for (int nt = 0; nt < 4; nt++) se += __expf(vals[nt] - rmax);
        #pragma unroll
        for (int d = 1; d < 16; d <<= 1) se += __shfl_xor(se, d, 64);
        if (c16 == 0)
          partials[(size_t)row * NT64 + (col0 >> 6) + wn] = make_float2(rmax, se);
      }
  }
}

// ---------------- attention: one block per (b, head, 8-query tile), bf16 in ----------------
__global__ __launch_bounds__(256) void attn_kernel(
    const __hip_bfloat16* __restrict__ q, const __hip_bfloat16* __restrict__ k,
    const __hip_bfloat16* __restrict__ v, const int* __restrict__ sep,
    __hip_bfloat16* __restrict__ ctx) {
  constexpr int QT = 8;
  int qt0 = blockIdx.x * QT;
  int h = blockIdx.y, b = blockIdx.z;
  __shared__ float qv[QT][DH];
  __shared__ float sc[QT][S];
  __shared__ float cpart[4][QT][DH];
  __shared__ float sinvs[QT];
  int tid = threadIdx.x;
  for (int i = tid; i < QT * DH; i += 256) {
    int qq = i >> 6, d = i & 63;
    qv[qq][d] = __bfloat162float(q[((size_t)(b * S + qt0 + qq)) * H + h * DH + d]);
  }
  __syncthreads();
  int sepb = sep[b];
  // scores: each thread handles 2 k-rows, reusing the row across 8 queries
  const unsigned short* kp = (const unsigned short*)k;
  for (int kk = tid; kk < S; kk += 256) {
    const uint4* kr = (const uint4*)(kp + ((size_t)(b * S + kk)) * H + h * DH);
    float accq[QT] = {};
    #pragma unroll
    for (int c = 0; c < 8; c++) {
      uint4 u = kr[c];
      float f0 = bflo(u.x), f1 = bfhi(u.x), f2 = bflo(u.y), f3 = bfhi(u.y);
      float f4 = bflo(u.z), f5 = bfhi(u.z), f6 = bflo(u.w), f7 = bfhi(u.w);
      #pragma unroll
      for (int qq = 0; qq < QT; qq++) {
        const float* qp = &qv[qq][c * 8];
        accq[qq] += f0 * qp[0] + f1 * qp[1] + f2 * qp[2] + f3 * qp[3]
                  + f4 * qp[4] + f5 * qp[5] + f6 * qp[6] + f7 * qp[7];
      }
    }
    #pragma unroll
    for (int qq = 0; qq < QT; qq++) {
      int qi = qt0 + qq;
      bool allowed = (kk <= qi) || (qi <= sepb && kk <= sepb);
      sc[qq][kk] = accq[qq] * 0.125f + (allowed ? 0.f : -1e4f);
    }
  }
  __syncthreads();
  // softmax: 32 threads per query
  {
    int qq = tid >> 5, t = tid & 31;
    float mx = -1e30f;
    for (int kk = t; kk < S; kk += 32) mx = fmaxf(mx, sc[qq][kk]);
    #pragma unroll
    for (int d2 = 1; d2 < 32; d2 <<= 1) mx = fmaxf(mx, __shfl_xor(mx, d2, 64));
    float ssum = 0.f;
    for (int kk = t; kk < S; kk += 32) {
      float e = __expf(sc[qq][kk] - mx);
      sc[qq][kk] = e;
      ssum += e;
    }
    #pragma unroll
    for (int d2 = 1; d2 < 32; d2 <<= 1) ssum += __shfl_xor(ssum, d2, 64);
    if (t == 0) sinvs[qq] = 1.0f / ssum;
  }
  __syncthreads();
  // PV: wave w handles k-rows [w*128, w*128+128), lane d accumulates 8 queries
  {
    int part = tid >> 6, d = tid & 63;
    const unsigned short* vp = (const unsigned short*)v;
    float acc8[QT] = {};
    for (int kk = part * 128; kk < part * 128 + 128; kk++) {
      float vv = __uint_as_float(((unsigned int)vp[((size_t)(b * S + kk)) * H + h * DH + d]) << 16);
      #pragma unroll
      for (int qq = 0; qq < QT; qq++) acc8[qq] += sc[qq][kk] * vv;
    }
    #pragma unroll
    for (int qq = 0; qq < QT; qq++) cpart[part][qq][d] = acc8[qq];
  }
  __syncthreads();
  for (int i = tid; i < QT * DH; i += 256) {
    int qq = i >> 6, d = i & 63;
    float r = (cpart[0][qq][d] + cpart[1][qq][d] + cpart[2][qq][d] + cpart[3][qq][d]) * sinvs[qq];
    ctx[((size_t)(b * S + qt0 + qq)) * H + h * DH + d] = __float2bfloat16(r);
  }
}

// ---------------- per-token nll + accumulate ----------------
__global__ __launch_bounds__(256) void loss_kernel(
    const float2* __restrict__ partials, const float* __restrict__ lablogit,
    const int* __restrict__ labels, float* __restrict__ acc) {
  int tok = blockIdx.x;
  if (labels[tok] < 0) return;
  __shared__ float red[256];
  float lm = -1e30f;
  for (int t = threadIdx.x; t < NT64; t += 256)
    lm = fmaxf(lm, partials[(size_t)tok * NT64 + t].x);
  float Mx = block_max256(lm, red);
  float ls = 0.f;
  for (int t = threadIdx.x; t < NT64; t += 256) {
    float2 p = partials[(size_t)tok * NT64 + t];
    ls += p.y * __expf(p.x - Mx);
  }
  float Ssum = block_sum256(ls, red);
  if (threadIdx.x == 0) {
    float nll = (Mx + logf(Ssum)) - lablogit[tok];
    atomicAdd(&acc[0], nll);
    atomicAdd(&acc[1], 1.0f);
  }
}

__global__ void finalize_kernel(const float* __restrict__ acc, float* __restrict__ out) {
  out[0] = acc[0] / fmaxf(acc[1], 1.0f);
}

}  // namespace

extern "C" void kernel_launch(void* const* d_in, const int* in_sizes, int n_in,
                              void* d_out, int out_size, void* d_ws, size_t ws_size,
                              hipStream_t stream) {
  const int*   input_ids = (const int*)d_in[0];
  const int*   labels    = (const int*)d_in[1];
  const float* word_emb  = (const float*)d_in[2];
  const float* pos_emb   = (const float*)d_in[3];
  const float* type_emb  = (const float*)d_in[4];
  const float* emb_ln_g  = (const float*)d_in[5];
  const float* emb_ln_b  = (const float*)d_in[6];
  const float* Wq = (const float*)d_in[7];
  const float* bq = (const float*)d_in[8];
  const float* Wk = (const float*)d_in[9];
  const float* bk = (const float*)d_in[10];
  const float* Wv = (const float*)d_in[11];
  const float* bv = (const float*)d_in[12];
  const float* Wo = (const float*)d_in[13];
  const float* bo = (const float*)d_in[14];
  const float* ln1_g = (const float*)d_in[15];
  const float* ln1_b = (const float*)d_in[16];
  const float* Wi = (const float*)d_in[17];
  const float* bi = (const float*)d_in[18];
  const float* Wd = (const float*)d_in[19];
  const float* bd = (const float*)d_in[20];
  const float* ln2_g = (const float*)d_in[21];
  const float* ln2_b = (const float*)d_in[22];
  const float* Wc = (const float*)d_in[23];
  const float* bc = (const float*)d_in[24];

  char* base = (char*)d_ws;
  size_t off = 0;
  auto alloc = [&](size_t bytes) -> void* {
    void* p = base + off;
    off = (off + bytes + 255) & ~(size_t)255;
    return p;
  };
  const size_t MH = (size_t)M * H;
  float*          x        = (float*)alloc(MH * 4);
  float*          t2       = (float*)alloc(MH * 4);
  __hip_bfloat16* xb       = (__hip_bfloat16*)alloc(MH * 2);
  __hip_bfloat16* qb       = (__hip_bfloat16*)alloc(MH * 2);
  __hip_bfloat16* kb       = (__hip_bfloat16*)alloc(MH * 2);
  __hip_bfloat16* vb       = (__hip_bfloat16*)alloc(MH * 2);
  __hip_bfloat16* ctxb     = (__hip_bfloat16*)alloc(MH * 2);
  __hip_bfloat16* t1b      = (__hip_bfloat16*)alloc((size_t)M * FF * 2);
  float2*         partials = (float2*)alloc((size_t)M * NT64 * 8);
  float*          lablogit = (float*)alloc((size_t)M * 4);
  float*          acc      = (float*)alloc(2 * 4);
  int*            sep      = (int*)alloc(B * 4);
  __hip_bfloat16* wq_t = (__hip_bfloat16*)alloc((size_t)LAYERS * H * H * 2);
  __hip_bfloat16* wk_t = (__hip_bfloat16*)alloc((size_t)LAYERS * H * H * 2);
  __hip_bfloat16* wv_t = (__hip_bfloat16*)alloc((size_t)LAYERS * H * H * 2);
  __hip_bfloat16* wo_t = (__hip_bfloat16*)alloc((size_t)LAYERS * H * H * 2);
  __hip_bfloat16* wi_t = (__hip_bfloat16*)alloc((size_t)FF * H * 2);      // per-layer reuse
  __hip_bfloat16* wd_t = (__hip_bfloat16*)alloc((size_t)H * FF * 2);      // per-layer reuse
  __hip_bfloat16* wc_t = (__hip_bfloat16*)alloc((size_t)NPAD * H * 2);

  hipMemsetAsync(acc, 0, 2 * sizeof(float), stream);

  sep_kernel<<<B, 256, 0, stream>>>(input_ids, sep);
  embed_kernel<<<M, 256, 0, stream>>>(input_ids, word_emb, pos_emb, type_emb,
                                      emb_ln_g, emb_ln_b, x, xb);

  // batched QKVO weight transposes (all layers)
  {
    dim3 tg(H / 32, H / 32, LAYERS);
    transpose_kernel<<<tg, 256, 0, stream>>>(Wq, wq_t, H, H, H, (size_t)H * H, (size_t)H * H);
    transpose_kernel<<<tg, 256, 0, stream>>>(Wk, wk_t, H, H, H, (size_t)H * H, (size_t)H * H);
    transpose_kernel<<<tg, 256, 0, stream>>>(Wv, wv_t, H, H, H, (size_t)H * H, (size_t)H * H);
    transpose_kernel<<<tg, 256, 0, stream>>>(Wo, wo_t, H, H, H, (size_t)H * H, (size_t)H * H);
    dim3 tgc(H / 32, NPAD / 32, 1);
    transpose_kernel<<<tgc, 256, 0, stream>>>(Wc, wc_t, H, V, NPAD, 0, 0);
  }

  dim3 gH(H / 128, M / 128);     // (6, 32)
  dim3 gF(FF / 128, M / 128);    // (24, 32)
  dim3 gAttn(S / 8, NH, B);      // (64, 12, 8)

  for (int l = 0; l < LAYERS; l++) {
    // per-layer FFN weight transposes into reused buffers
    transpose_kernel<<<dim3(H / 32, FF / 32, 1), 256, 0, stream>>>(
        Wi + (size_t)l * H * FF, wi_t, H, FF, FF, 0, 0);
    transpose_kernel<<<dim3(FF / 32, H / 32, 1), 256, 0, stream>>>(
        Wd + (size_t)l * FF * H, wd_t, FF, H, H, 0, 0);

    const short* xbs = (const short*)xb;
    mfma_gemm<H, H, 1><<<gH, 256, 0, stream>>>(
        xbs, (const short*)(wq_t + (size_t)l * H * H), bq + (size_t)l * H,
        nullptr, qb, nullptr, nullptr, nullptr);
    mfma_gemm<H, H, 1><<<gH, 256, 0, stream>>>(
        xbs, (const short*)(wk_t + (size_t)l * H * H), bk + (size_t)l * H,
        nullptr, kb, nullptr, nullptr, nullptr);
    mfma_gemm<H, H, 1><<<gH, 256, 0, stream>>>(
        xbs, (const short*)(wv_t + (size_t)l * H * H), bv + (size_t)l * H,
        nullptr, vb, nullptr, nullptr, nullptr);
    attn_kernel<<<gAttn, 256, 0, stream>>>(qb, kb, vb, sep, ctxb);
    mfma_gemm<H, H, 0><<<gH, 256, 0, stream>>>(
        (const short*)ctxb, (const short*)(wo_t + (size_t)l * H * H), bo + (size_t)l * H,
        t2, nullptr, nullptr, nullptr, nullptr);
    add_ln_kernel<<<M, 256, 0, stream>>>(x, t2, ln1_g + (size_t)l * H,
                                         ln1_b + (size_t)l * H, x, xb);
    mfma_gemm<H, FF, 2><<<gF, 256, 0, stream>>>(
        (const short*)xb, (const short*)wi_t, bi + (size_t)l * FF,
        nullptr, t1b, nullptr, nullptr, nullptr);
    mfma_gemm<FF, H, 0><<<gH, 256, 0, stream>>>(
        (const short*)t1b, (const short*)wd_t, bd + (size_t)l * H,
        t2, nullptr, nullptr, nullptr, nullptr);
    add_ln_kernel<<<M, 256, 0, stream>>>(x, t2, ln2_g + (size_t)l * H,
                                         ln2_b + (size_t)l * H, x, xb);
  }

  dim3 gV(NPAD / 128, M / 128);  // (166, 32)
  mfma_gemm<H, NPAD, 3><<<gV, 256, 0, stream>>>(
      (const short*)xb, (const short*)wc_t, bc,
      nullptr, nullptr, labels, partials, lablogit);
  loss_kernel<<<M, 256, 0, stream>>>(partials, lablogit, labels, acc);
  finalize_kernel<<<1, 1, 0, stream>>>(acc, (float*)d_out);
}

// Round 3
// 3600.392 us; speedup vs baseline: 8.0550x; 2.5251x over previous
//
#include <hip/hip_runtime.h>
#include <hip/hip_bf16.h>
#include <cmath>

namespace {

constexpr int LAYERS = 12;
constexpr int H   = 768;
constexpr int NH  = 12;
constexpr int DH  = 64;
constexpr int FF  = 3072;
constexpr int V   = 21128;
constexpr int S   = 512;
constexpr int B   = 8;
constexpr int M   = B * S;            // 4096 tokens
constexpr int SEP = 102;
constexpr int NPAD = 21248;           // V padded to multiple of 128
constexpr int NT64 = NPAD / 64;       // 332 column half-tiles for logits

typedef __attribute__((ext_vector_type(8))) short short8;
typedef __attribute__((ext_vector_type(4))) float floatx4;

__device__ __forceinline__ float geluf(float x) {
  return 0.5f * x * (1.0f + erff(x * 0.70710678118654752f));
}

__device__ __forceinline__ void gload16(const void* g, void* l) {
  __builtin_amdgcn_global_load_lds(
      (const __attribute__((address_space(1))) void*)g,
      (__attribute__((address_space(3))) void*)l, 16, 0, 0);
}

__device__ __forceinline__ unsigned short f2bf(float f) {
  __hip_bfloat16 h = __float2bfloat16(f);
  return *reinterpret_cast<unsigned short*>(&h);
}

__device__ __forceinline__ float block_sum256(float v, float* red) {
  int tid = threadIdx.x;
  red[tid] = v; __syncthreads();
  for (int s2 = 128; s2 > 0; s2 >>= 1) {
    if (tid < s2) red[tid] += red[tid + s2];
    __syncthreads();
  }
  float r = red[0];
  __syncthreads();
  return r;
}

__device__ __forceinline__ float block_max256(float v, float* red) {
  int tid = threadIdx.x;
  red[tid] = v; __syncthreads();
  for (int s2 = 128; s2 > 0; s2 >>= 1) {
    if (tid < s2) red[tid] = fmaxf(red[tid], red[tid + s2]);
    __syncthreads();
  }
  float r = red[0];
  __syncthreads();
  return r;
}

// ---------------- sep position per batch row ----------------
__global__ void sep_kernel(const int* __restrict__ ids, int* __restrict__ sep) {
  int b = blockIdx.x;
  __shared__ int red[256];
  int m = S - 1;
  for (int s = threadIdx.x; s < S; s += 256)
    if (ids[b * S + s] == SEP) m = min(m, s);
  red[threadIdx.x] = m; __syncthreads();
  for (int s2 = 128; s2 > 0; s2 >>= 1) {
    if (threadIdx.x < s2) red[threadIdx.x] = min(red[threadIdx.x], red[threadIdx.x + s2]);
    __syncthreads();
  }
  if (threadIdx.x == 0) sep[b] = red[0];
}

// ---------------- weight transpose + f32->bf16: W[K,N] -> Wt[Npad,K] ----------------
__global__ __launch_bounds__(256) void transpose_kernel(
    const float* __restrict__ W, __hip_bfloat16* __restrict__ Wt,
    int K, int N, int Npad, size_t in_stride, size_t out_stride) {
  const float* Wz = W + (size_t)blockIdx.z * in_stride;
  __hip_bfloat16* Wtz = Wt + (size_t)blockIdx.z * out_stride;
  __shared__ float tile[32][33];
  int k0 = blockIdx.x * 32, n0 = blockIdx.y * 32;
  int tx = threadIdx.x & 31, ty = threadIdx.x >> 5;  // 32 x 8
  #pragma unroll
  for (int i = 0; i < 4; i++) {
    int kk = k0 + ty + i * 8, nn = n0 + tx;
    tile[ty + i * 8][tx] = (kk < K && nn < N) ? Wz[(size_t)kk * N + nn] : 0.f;
  }
  __syncthreads();
  #pragma unroll
  for (int i = 0; i < 4; i++) {
    int nn = n0 + ty + i * 8, kk = k0 + tx;
    if (nn < Npad && kk < K)
      Wtz[(size_t)nn * K + kk] = __float2bfloat16(tile[tx][ty + i * 8]);
  }
}

// ---------------- embedding + LN (writes f32 x and bf16 xb) ----------------
__global__ __launch_bounds__(256) void embed_kernel(
    const int* __restrict__ ids, const float* __restrict__ we,
    const float* __restrict__ pe, const float* __restrict__ te,
    const float* __restrict__ g, const float* __restrict__ bta,
    float* __restrict__ x, __hip_bfloat16* __restrict__ xb) {
  __shared__ float red[256];
  int tok = blockIdx.x;
  int s = tok % S;
  int id = ids[tok];
  float vals[3];
  #pragma unroll
  for (int i = 0; i < 3; i++) {
    int hh = threadIdx.x + i * 256;
    vals[i] = we[(size_t)id * H + hh] + pe[(size_t)s * H + hh] + te[hh];
  }
  float mean = block_sum256(vals[0] + vals[1] + vals[2], red) * (1.0f / H);
  float sq = 0.f;
  #pragma unroll
  for (int i = 0; i < 3; i++) { float d = vals[i] - mean; sq += d * d; }
  float var = block_sum256(sq, red) * (1.0f / H);
  float inv = rsqrtf(var + 1e-12f);
  #pragma unroll
  for (int i = 0; i < 3; i++) {
    int hh = threadIdx.x + i * 256;
    float o = (vals[i] - mean) * inv * g[hh] + bta[hh];
    x[(size_t)tok * H + hh] = o;
    xb[(size_t)tok * H + hh] = __float2bfloat16(o);
  }
}

// ---------------- residual + LN (writes f32 x and bf16 xb) ----------------
__global__ __launch_bounds__(256) void add_ln_kernel(
    const float* __restrict__ resid, const float* __restrict__ t,
    const float* __restrict__ g, const float* __restrict__ bta,
    float* __restrict__ out, __hip_bfloat16* __restrict__ outb) {
  __shared__ float red[256];
  int tok = blockIdx.x;
  float vals[3];
  #pragma unroll
  for (int i = 0; i < 3; i++) {
    int hh = threadIdx.x + i * 256;
    vals[i] = resid[(size_t)tok * H + hh] + t[(size_t)tok * H + hh];
  }
  float mean = block_sum256(vals[0] + vals[1] + vals[2], red) * (1.0f / H);
  float sq = 0.f;
  #pragma unroll
  for (int i = 0; i < 3; i++) { float d = vals[i] - mean; sq += d * d; }
  float var = block_sum256(sq, red) * (1.0f / H);
  float inv = rsqrtf(var + 1e-12f);
  #pragma unroll
  for (int i = 0; i < 3; i++) {
    int hh = threadIdx.x + i * 256;
    float o = (vals[i] - mean) * inv * g[hh] + bta[hh];
    out[(size_t)tok * H + hh] = o;
    outb[(size_t)tok * H + hh] = __float2bfloat16(o);
  }
}

// ---------------- MFMA bf16 GEMM: C = epi(A @ Bt^T + bias) ----------------
// EPI: 0 = f32 store; 1 = bf16 store; 2 = gelu + bf16 store; 3 = logits partials;
//      4 = bf16 store transposed into vt[b][h][d][s] (for attention PV operand).
template <int K, int N, int EPI>
__global__ __launch_bounds__(256) void mfma_gemm(
    const short* __restrict__ A, const short* __restrict__ Bt,
    const float* __restrict__ bias,
    float* __restrict__ Cf, __hip_bfloat16* __restrict__ Cb,
    const int* __restrict__ labels, float2* __restrict__ partials,
    float* __restrict__ lablogit) {
  __shared__ __align__(16) short lds_a[128 * 32];
  __shared__ __align__(16) short lds_b[128 * 32];
  const int tid = threadIdx.x, lane = tid & 63, w = tid >> 6;
  const int wm = w >> 1, wn = w & 1;
  const int row0 = blockIdx.y * 128, col0 = blockIdx.x * 128;
  const int g = lane >> 4, c16 = lane & 15;
  const int srow = w * 32 + (lane >> 2);
  const int schunk = lane & 3;
  floatx4 acc[4][4] = {};

  for (int k0 = 0; k0 < K; k0 += 32) {
    #pragma unroll
    for (int j = 0; j < 2; j++) {
      int m = srow + j * 16;
      int cg = schunk ^ ((m >> 1) & 3);
      gload16(A + (size_t)(row0 + m) * K + (k0 + cg * 8), lds_a + w * 1024 + j * 512);
      gload16(Bt + (size_t)(col0 + m) * K + (k0 + cg * 8), lds_b + w * 1024 + j * 512);
    }
    __syncthreads();
    short8 af[4], bfr[4];
    #pragma unroll
    for (int t = 0; t < 4; t++) {
      int rm = wm * 64 + t * 16 + c16;
      af[t] = *(const short8*)(lds_a + rm * 32 + ((g ^ ((rm >> 1) & 3)) << 3));
      int rn = wn * 64 + t * 16 + c16;
      bfr[t] = *(const short8*)(lds_b + rn * 32 + ((g ^ ((rn >> 1) & 3)) << 3));
    }
    #pragma unroll
    for (int mt = 0; mt < 4; mt++)
      #pragma unroll
      for (int nt = 0; nt < 4; nt++)
        acc[mt][nt] = __builtin_amdgcn_mfma_f32_16x16x32_bf16(af[mt], bfr[nt], acc[mt][nt], 0, 0, 0);
    __syncthreads();
  }

  if constexpr (EPI == 0) {
    #pragma unroll
    for (int mt = 0; mt < 4; mt++)
      #pragma unroll
      for (int r = 0; r < 4; r++) {
        int row = row0 + wm * 64 + mt * 16 + g * 4 + r;
        #pragma unroll
        for (int nt = 0; nt < 4; nt++) {
          int col = col0 + wn * 64 + nt * 16 + c16;
          Cf[(size_t)row * N + col] = acc[mt][nt][r] + bias[col];
        }
      }
  } else if constexpr (EPI == 1 || EPI == 2) {
    #pragma unroll
    for (int mt = 0; mt < 4; mt++)
      #pragma unroll
      for (int r = 0; r < 4; r++) {
        int row = row0 + wm * 64 + mt * 16 + g * 4 + r;
        #pragma unroll
        for (int nt = 0; nt < 4; nt++) {
          int col = col0 + wn * 64 + nt * 16 + c16;
          float vv = acc[mt][nt][r] + bias[col];
          if constexpr (EPI == 2) vv = geluf(vv);
          Cb[(size_t)row * N + col] = __float2bfloat16(vv);
        }
      }
  } else if constexpr (EPI == 4) {
    // V projection written transposed: vt[((b*NH+h)*DH+d)*S + s], r -> s consecutive
    unsigned short* vt = (unsigned short*)Cb;
    #pragma unroll
    for (int mt = 0; mt < 4; mt++) {
      int row = row0 + wm * 64 + mt * 16 + g * 4;   // token for r=0
      int bb = row >> 9, s0 = row & 511;
      #pragma unroll
      for (int nt = 0; nt < 4; nt++) {
        int col = col0 + wn * 64 + nt * 16 + c16;
        int h = col >> 6, d = col & 63;
        float bcol = bias[col];
        uint2 u;
        unsigned short p0 = f2bf(acc[mt][nt][0] + bcol);
        unsigned short p1 = f2bf(acc[mt][nt][1] + bcol);
        unsigned short p2 = f2bf(acc[mt][nt][2] + bcol);
        unsigned short p3 = f2bf(acc[mt][nt][3] + bcol);
        u.x = (unsigned int)p0 | ((unsigned int)p1 << 16);
        u.y = (unsigned int)p2 | ((unsigned int)p3 << 16);
        *(uint2*)(vt + ((size_t)((bb * NH + h) * DH + d) << 9) + s0) = u;
      }
    }
  } else {
    #pragma unroll
    for (int mt = 0; mt < 4; mt++)
      #pragma unroll
      for (int r = 0; r < 4; r++) {
        int row = row0 + wm * 64 + mt * 16 + g * 4 + r;
        int lab = labels[row];
        float vals[4];
        float rmax = -1e30f;
        #pragma unroll
        for (int nt = 0; nt < 4; nt++) {
          int col = col0 + wn * 64 + nt * 16 + c16;
          float vv = (col < V) ? (acc[mt][nt][r] + bias[col]) : -60000.0f;
          vals[nt] = vv;
          rmax = fmaxf(rmax, vv);
          if (col == lab) lablogit[row] = vv;
        }
        #pragma unroll
        for (int d = 1; d < 16; d <<= 1) rmax = fmaxf(rmax, __shfl_xor(rmax, d, 64));
        float se = 0.f;
        #pragma unroll
        for (int nt = 0; nt < 4; nt++) se += __expf(vals[nt] - rmax);
        #pragma unroll
        for (int d = 1; d < 16; d <<= 1) se += __shfl_xor(se, d, 64);
        if (c16 == 0)
          partials[(size_t)row * NT64 + (col0 >> 6) + wn] = make_float2(rmax, se);
      }
  }
}

// ---------------- MFMA flash attention ----------------
// Block = (qtile of 64, head, batch). Computes Sc^T = K·Q^T per 128-k-tile
// (A = K rows, B = Q rows, both natural [seq][d] layout), online softmax,
// P^T -> LDS (kk-consecutive b64 writes), then O = P·V^T with Vt[b][h][d][s].
__global__ __launch_bounds__(256) void flash_attn(
    const short* __restrict__ q, const short* __restrict__ k,
    const short* __restrict__ vt, const int* __restrict__ sep,
    __hip_bfloat16* __restrict__ ctx) {
  constexpr int KT = 128;
  __shared__ __align__(16) short Qs[64 * 64];
  __shared__ __align__(16) short Ks[128 * 64];
  __shared__ __align__(16) short Vts[64 * 128];
  __shared__ __align__(16) short Pb[64 * 136];
  __shared__ __align__(16) float wm4[4][64];
  __shared__ __align__(16) float wl4[4][64];
  __shared__ __align__(16) float m_run[64], l_run[64], alpha_s[64], mnew_s[64];

  const int tid = threadIdx.x, lane = tid & 63, w = tid >> 6;
  const int g = lane >> 4, c16 = lane & 15;
  const int qt0 = blockIdx.x * 64, h = blockIdx.y, b = blockIdx.z;
  const int sepb = sep[b];

  if (tid < 64) { m_run[tid] = -1e30f; l_run[tid] = 0.f; }

  // stage Q tile [64 q][64 d], chunk-swizzled: slot = c ^ (row&7)
  #pragma unroll
  for (int t = 0; t < 2; t++) {
    int id = (w * 2 + t) * 64 + lane;
    int row = id >> 3, slot = id & 7;
    int c = slot ^ (row & 7);
    gload16(q + (size_t)(b * S + qt0 + row) * H + h * DH + c * 8,
            Qs + (w * 2 + t) * 512);
  }

  int niter = (qt0 + 64 + KT - 1) / KT;
  int sepit = (sepb >> 7) + 1;
  if (sepit > niter) niter = sepit;

  floatx4 accO[4] = {};
  short8 qf[4][2];

  for (int it = 0; it < niter; ++it) {
    int kk0 = it * KT;
    __syncthreads();   // prev iteration's LDS reads complete
    // stage K tile [128 kk][64 d] and Vt tile [64 d][128 kk]
    #pragma unroll
    for (int t = 0; t < 4; t++) {
      int id = (w * 4 + t) * 64 + lane;
      {
        int row = id >> 3, slot = id & 7, c = slot ^ (row & 7);
        gload16(k + (size_t)(b * S + kk0 + row) * H + h * DH + c * 8,
                Ks + (w * 4 + t) * 512);
      }
      {
        int row = id >> 4, slot = id & 15, c = slot ^ (row & 15);
        gload16(vt + (size_t)((b * NH + h) * DH + row) * S + kk0 + c * 8,
                Vts + (w * 4 + t) * 512);
      }
    }
    __syncthreads();   // staging complete (drains vmcnt)

    if (it == 0) {
      #pragma unroll
      for (int nt = 0; nt < 4; nt++)
        #pragma unroll
        for (int st = 0; st < 2; st++) {
          int qq = nt * 16 + c16;
          int slot = (st * 4 + g) ^ (qq & 7);
          qf[nt][st] = *(const short8*)(Qs + qq * 64 + slot * 8);
        }
    }

    // Sc^T [128 kk][64 q]: wave w owns kk rows [w*32, w*32+32)
    floatx4 accS[2][4] = {};
    #pragma unroll
    for (int st = 0; st < 2; st++) {
      short8 af[2];
      #pragma unroll
      for (int mt = 0; mt < 2; mt++) {
        int kkr = w * 32 + mt * 16 + c16;
        int slot = (st * 4 + g) ^ (kkr & 7);
        af[mt] = *(const short8*)(Ks + kkr * 64 + slot * 8);
      }
      #pragma unroll
      for (int mt = 0; mt < 2; mt++)
        #pragma unroll
        for (int nt = 0; nt < 4; nt++)
          accS[mt][nt] = __builtin_amdgcn_mfma_f32_16x16x32_bf16(
              af[mt], qf[nt][st], accS[mt][nt], 0, 0, 0);
    }

    // mask + scale; per-lane max per q
    float sc[2][4][4];
    float pm[4] = {-1e30f, -1e30f, -1e30f, -1e30f};
    #pragma unroll
    for (int mt = 0; mt < 2; mt++)
      #pragma unroll
      for (int nt = 0; nt < 4; nt++)
        #pragma unroll
        for (int r = 0; r < 4; r++) {
          int kkg = kk0 + w * 32 + mt * 16 + g * 4 + r;
          int qg = qt0 + nt * 16 + c16;
          bool allowed = (kkg <= qg) || (qg <= sepb && kkg <= sepb);
          float vv = accS[mt][nt][r] * 0.125f + (allowed ? 0.f : -1e4f);
          sc[mt][nt][r] = vv;
          pm[nt] = fmaxf(pm[nt], vv);
        }
    #pragma unroll
    for (int nt = 0; nt < 4; nt++) {
      pm[nt] = fmaxf(pm[nt], __shfl_xor(pm[nt], 16, 64));
      pm[nt] = fmaxf(pm[nt], __shfl_xor(pm[nt], 32, 64));
    }
    if (lane < 16) {
      #pragma unroll
      for (int nt = 0; nt < 4; nt++) wm4[w][nt * 16 + c16] = pm[nt];
    }
    __syncthreads();
    if (tid < 64) {
      float mit = fmaxf(fmaxf(wm4[0][tid], wm4[1][tid]), fmaxf(wm4[2][tid], wm4[3][tid]));
      float mold = m_run[tid];
      float mnew = fmaxf(mold, mit);
      float al = __expf(mold - mnew);
      m_run[tid] = mnew;
      alpha_s[tid] = al;
      mnew_s[tid] = mnew;
      l_run[tid] *= al;
    }
    __syncthreads();

    // P = exp(sc - mnew); write P^T to Pb[q][kk] (4 kk-consecutive bf16 per write)
    float psum[4] = {};
    #pragma unroll
    for (int mt = 0; mt < 2; mt++)
      #pragma unroll
      for (int nt = 0; nt < 4; nt++) {
        int qg = nt * 16 + c16;
        float mn = mnew_s[qg];
        unsigned short pk[4];
        #pragma unroll
        for (int r = 0; r < 4; r++) {
          float p = __expf(sc[mt][nt][r] - mn);
          psum[nt] += p;
          pk[r] = f2bf(p);
        }
        int kb = w * 32 + mt * 16 + g * 4;
        uint2 u;
        u.x = (unsigned int)pk[0] | ((unsigned int)pk[1] << 16);
        u.y = (unsigned int)pk[2] | ((unsigned int)pk[3] << 16);
        *(uint2*)(Pb + qg * 136 + kb) = u;
      }
    #pragma unroll
    for (int nt = 0; nt < 4; nt++) {
      psum[nt] += __shfl_xor(psum[nt], 16, 64);
      psum[nt] += __shfl_xor(psum[nt], 32, 64);
    }
    if (lane < 16) {
      #pragma unroll
      for (int nt = 0; nt < 4; nt++) wl4[w][nt * 16 + c16] = psum[nt];
    }
    // rescale O accumulators (wave w owns q rows w*16 + g*4 + r)
    {
      float4 a4 = *(const float4*)(alpha_s + w * 16 + g * 4);
      #pragma unroll
      for (int nt = 0; nt < 4; nt++) {
        accO[nt][0] *= a4.x; accO[nt][1] *= a4.y;
        accO[nt][2] *= a4.z; accO[nt][3] *= a4.w;
      }
    }
    __syncthreads();   // Pb + wl4 visible
    if (tid < 64)
      l_run[tid] += wl4[0][tid] + wl4[1][tid] + wl4[2][tid] + wl4[3][tid];

    // O[64 q][64 d] += P · V^T ; wave w owns q rows [w*16, w*16+16)
    #pragma unroll
    for (int st = 0; st < 4; st++) {
      short8 pf = *(const short8*)(Pb + (w * 16 + c16) * 136 + st * 32 + g * 8);
      #pragma unroll
      for (int nt = 0; nt < 4; nt++) {
        int d = nt * 16 + c16;
        int slot = (st * 4 + g) ^ (d & 15);
        short8 vf = *(const short8*)(Vts + d * 128 + slot * 8);
        accO[nt] = __builtin_amdgcn_mfma_f32_16x16x32_bf16(pf, vf, accO[nt], 0, 0, 0);
      }
    }
  }

  __syncthreads();
  float4 lv = *(const float4*)(l_run + w * 16 + g * 4);
  float linv[4] = {1.0f / lv.x, 1.0f / lv.y, 1.0f / lv.z, 1.0f / lv.w};
  #pragma unroll
  for (int r = 0; r < 4; r++) {
    int row = b * S + qt0 + w * 16 + g * 4 + r;
    #pragma unroll
    for (int nt = 0; nt < 4; nt++)
      ctx[(size_t)row * H + h * DH + nt * 16 + c16] =
          __float2bfloat16(accO[nt][r] * linv[r]);
  }
}

// ---------------- per-token nll + accumulate ----------------
__global__ __launch_bounds__(256) void loss_kernel(
    const float2* __restrict__ partials, const float* __restrict__ lablogit,
    const int* __restrict__ labels, float* __restrict__ acc) {
  int tok = blockIdx.x;
  if (labels[tok] < 0) return;
  __shared__ float red[256];
  float lm = -1e30f;
  for (int t = threadIdx.x; t < NT64; t += 256)
    lm = fmaxf(lm, partials[(size_t)tok * NT64 + t].x);
  float Mx = block_max256(lm, red);
  float ls = 0.f;
  for (int t = threadIdx.x; t < NT64; t += 256) {
    float2 p = partials[(size_t)tok * NT64 + t];
    ls += p.y * __expf(p.x - Mx);
  }
  float Ssum = block_sum256(ls, red);
  if (threadIdx.x == 0) {
    float nll = (Mx + logf(Ssum)) - lablogit[tok];
    atomicAdd(&acc[0], nll);
    atomicAdd(&acc[1], 1.0f);
  }
}

__global__ void finalize_kernel(const float* __restrict__ acc, float* __restrict__ out) {
  out[0] = acc[0] / fmaxf(acc[1], 1.0f);
}

}  // namespace

extern "C" void kernel_launch(void* const* d_in, const int* in_sizes, int n_in,
                              void* d_out, int out_size, void* d_ws, size_t ws_size,
                              hipStream_t stream) {
  const int*   input_ids = (const int*)d_in[0];
  const int*   labels    = (const int*)d_in[1];
  const float* word_emb  = (const float*)d_in[2];
  const float* pos_emb   = (const float*)d_in[3];
  const float* type_emb  = (const float*)d_in[4];
  const float* emb_ln_g  = (const float*)d_in[5];
  const float* emb_ln_b  = (const float*)d_in[6];
  const float* Wq = (const float*)d_in[7];
  const float* bq = (const float*)d_in[8];
  const float* Wk = (const float*)d_in[9];
  const float* bk = (const float*)d_in[10];
  const float* Wv = (const float*)d_in[11];
  const float* bv = (const float*)d_in[12];
  const float* Wo = (const float*)d_in[13];
  const float* bo = (const float*)d_in[14];
  const float* ln1_g = (const float*)d_in[15];
  const float* ln1_b = (const float*)d_in[16];
  const float* Wi = (const float*)d_in[17];
  const float* bi = (const float*)d_in[18];
  const float* Wd = (const float*)d_in[19];
  const float* bd = (const float*)d_in[20];
  const float* ln2_g = (const float*)d_in[21];
  const float* ln2_b = (const float*)d_in[22];
  const float* Wc = (const float*)d_in[23];
  const float* bc = (const float*)d_in[24];

  char* base = (char*)d_ws;
  size_t off = 0;
  auto alloc = [&](size_t bytes) -> void* {
    void* p = base + off;
    off = (off + bytes + 255) & ~(size_t)255;
    return p;
  };
  const size_t MH = (size_t)M * H;
  float*          x        = (float*)alloc(MH * 4);
  float*          t2       = (float*)alloc(MH * 4);
  __hip_bfloat16* xb       = (__hip_bfloat16*)alloc(MH * 2);
  __hip_bfloat16* qb       = (__hip_bfloat16*)alloc(MH * 2);
  __hip_bfloat16* kb       = (__hip_bfloat16*)alloc(MH * 2);
  __hip_bfloat16* vt       = (__hip_bfloat16*)alloc((size_t)B * NH * DH * S * 2);
  __hip_bfloat16* ctxb     = (__hip_bfloat16*)alloc(MH * 2);
  __hip_bfloat16* t1b      = (__hip_bfloat16*)alloc((size_t)M * FF * 2);
  float2*         partials = (float2*)alloc((size_t)M * NT64 * 8);
  float*          lablogit = (float*)alloc((size_t)M * 4);
  float*          acc      = (float*)alloc(2 * 4);
  int*            sep      = (int*)alloc(B * 4);
  __hip_bfloat16* wq_t = (__hip_bfloat16*)alloc((size_t)LAYERS * H * H * 2);
  __hip_bfloat16* wk_t = (__hip_bfloat16*)alloc((size_t)LAYERS * H * H * 2);
  __hip_bfloat16* wv_t = (__hip_bfloat16*)alloc((size_t)LAYERS * H * H * 2);
  __hip_bfloat16* wo_t = (__hip_bfloat16*)alloc((size_t)LAYERS * H * H * 2);
  __hip_bfloat16* wi_t = (__hip_bfloat16*)alloc((size_t)FF * H * 2);
  __hip_bfloat16* wd_t = (__hip_bfloat16*)alloc((size_t)H * FF * 2);
  __hip_bfloat16* wc_t = (__hip_bfloat16*)alloc((size_t)NPAD * H * 2);

  hipMemsetAsync(acc, 0, 2 * sizeof(float), stream);

  sep_kernel<<<B, 256, 0, stream>>>(input_ids, sep);
  embed_kernel<<<M, 256, 0, stream>>>(input_ids, word_emb, pos_emb, type_emb,
                                      emb_ln_g, emb_ln_b, x, xb);

  {
    dim3 tg(H / 32, H / 32, LAYERS);
    transpose_kernel<<<tg, 256, 0, stream>>>(Wq, wq_t, H, H, H, (size_t)H * H, (size_t)H * H);
    transpose_kernel<<<tg, 256, 0, stream>>>(Wk, wk_t, H, H, H, (size_t)H * H, (size_t)H * H);
    transpose_kernel<<<tg, 256, 0, stream>>>(Wv, wv_t, H, H, H, (size_t)H * H, (size_t)H * H);
    transpose_kernel<<<tg, 256, 0, stream>>>(Wo, wo_t, H, H, H, (size_t)H * H, (size_t)H * H);
    dim3 tgc(H / 32, NPAD / 32, 1);
    transpose_kernel<<<tgc, 256, 0, stream>>>(Wc, wc_t, H, V, NPAD, 0, 0);
  }

  dim3 gH(H / 128, M / 128);     // (6, 32)
  dim3 gF(FF / 128, M / 128);    // (24, 32)
  dim3 gAttn(S / 64, NH, B);     // (8, 12, 8) = 768 blocks

  for (int l = 0; l < LAYERS; l++) {
    transpose_kernel<<<dim3(H / 32, FF / 32, 1), 256, 0, stream>>>(
        Wi + (size_t)l * H * FF, wi_t, H, FF, FF, 0, 0);
    transpose_kernel<<<dim3(FF / 32, H / 32, 1), 256, 0, stream>>>(
        Wd + (size_t)l * FF * H, wd_t, FF, H, H, 0, 0);

    const short* xbs = (const short*)xb;
    mfma_gemm<H, H, 1><<<gH, 256, 0, stream>>>(
        xbs, (const short*)(wq_t + (size_t)l * H * H), bq + (size_t)l * H,
        nullptr, qb, nullptr, nullptr, nullptr);
    mfma_gemm<H, H, 1><<<gH, 256, 0, stream>>>(
        xbs, (const short*)(wk_t + (size_t)l * H * H), bk + (size_t)l * H,
        nullptr, kb, nullptr, nullptr, nullptr);
    mfma_gemm<H, H, 4><<<gH, 256, 0, stream>>>(
        xbs, (const short*)(wv_t + (size_t)l * H * H), bv + (size_t)l * H,
        nullptr, vt, nullptr, nullptr, nullptr);
    flash_attn<<<gAttn, 256, 0, stream>>>(
        (const short*)qb, (const short*)kb, (const short*)vt, sep, ctxb);
    mfma_gemm<H, H, 0><<<gH, 256, 0, stream>>>(
        (const short*)ctxb, (const short*)(wo_t + (size_t)l * H * H), bo + (size_t)l * H,
        t2, nullptr, nullptr, nullptr, nullptr);
    add_ln_kernel<<<M, 256, 0, stream>>>(x, t2, ln1_g + (size_t)l * H,
                                         ln1_b + (size_t)l * H, x, xb);
    mfma_gemm<H, FF, 2><<<gF, 256, 0, stream>>>(
        (const short*)xb, (const short*)wi_t, bi + (size_t)l * FF,
        nullptr, t1b, nullptr, nullptr, nullptr);
    mfma_gemm<FF, H, 0><<<gH, 256, 0, stream>>>(
        (const short*)t1b, (const short*)wd_t, bd + (size_t)l * H,
        t2, nullptr, nullptr, nullptr, nullptr);
    add_ln_kernel<<<M, 256, 0, stream>>>(x, t2, ln2_g + (size_t)l * H,
                                         ln2_b + (size_t)l * H, x, xb);
  }

  dim3 gV(NPAD / 128, M / 128);  // (166, 32)
  mfma_gemm<H, NPAD, 3><<<gV, 256, 0, stream>>>(
      (const short*)xb, (const short*)wc_t, bc,
      nullptr, nullptr, labels, partials, lablogit);
  loss_kernel<<<M, 256, 0, stream>>>(partials, lablogit, labels, acc);
  finalize_kernel<<<1, 1, 0, stream>>>(acc, (float*)d_out);
}